// Round 10
// baseline (264.546 us; speedup 1.0000x reference)
//
#include <hip/hip_runtime.h>

// Lorenz RK4, B=16384, NT=2000, dt=0.01. out[b*6003 + d*2001 + t].
//
// Round-6: checkpoint/replay time-split.
//  Phase 1 (lorenz_coarse): pure-register compute of steps 1..1000,
//    checkpoint state -> d_ws. No LDS, no barriers. 256 blocks x 64.
//  Phase 2 (lorenz_fine): 512 blocks x 192 (2 blocks/CU). Lower 256 blocks
//    replay steps 1..1000 writing output; upper 256 start from checkpoint
//    and run steps 1001..2000 writing output. Producer/consumer structure
//    of rounds 3-5 (1 compute wave + 2 writer waves, TT=32 double buffer,
//    LDS 49.9KB -> two blocks fit per CU).
//  Replay is bit-identical to continuous integration: absmax must stay
//  exactly 0.0078125.

#define TROWS  2001
#define ROWS   64
#define LROWS  65
#define TT     32
#define HALF   1000
#define NFULL  31          // 31 full tiles of 32 + 8 tail = 1000
#define TAIL   8

#define FMA(a,b,c) __builtin_fmaf((a),(b),(c))

#define STEP() do {                                                          \
        float k1x = p0 * (y - x);                                            \
        float k1y = FMA(x, p1 - z, -y);                                      \
        float k1z = FMA(p2n, z, x * y);                                      \
        float ax = FMA(h2,k1x,x), ay = FMA(h2,k1y,y), az = FMA(h2,k1z,z);    \
        float k2x = p0 * (ay - ax);                                          \
        float k2y = FMA(ax, p1 - az, -ay);                                   \
        float k2z = FMA(p2n, az, ax * ay);                                   \
        float bx = FMA(h2,k2x,x), by = FMA(h2,k2y,y), bz = FMA(h2,k2z,z);    \
        float k3x = p0 * (by - bx);                                          \
        float k3y = FMA(bx, p1 - bz, -by);                                   \
        float k3z = FMA(p2n, bz, bx * by);                                   \
        float cx = FMA(h1,k3x,x), cy = FMA(h1,k3y,y), cz = FMA(h1,k3z,z);    \
        float k4x = p0 * (cy - cx);                                          \
        float k4y = FMA(cx, p1 - cz, -cy);                                   \
        float k4z = FMA(p2n, cz, cx * cy);                                   \
        float sx = FMA(2.0f,k2x,k1x); sx = FMA(2.0f,k3x,sx); sx += k4x;      \
        float sy = FMA(2.0f,k2y,k1y); sy = FMA(2.0f,k3y,sy); sy += k4y;      \
        float sz = FMA(2.0f,k2z,k1z); sz = FMA(2.0f,k3z,sz); sz += k4z;      \
        x = FMA(h6,sx,x); y = FMA(h6,sy,y); z = FMA(h6,sz,z);                \
    } while (0)

__global__ __launch_bounds__(64) void lorenz_coarse(
    const float* __restrict__ x0,
    const float* __restrict__ p,
    float* __restrict__ ckpt)
{
#pragma clang fp contract(off)
    const int lane = threadIdx.x;
    const int b = blockIdx.x * 64 + lane;
    const float p0 = p[0], p1 = p[1], p2n = -p[2];
    const float h1 = 0.01f, h2 = 0.01f / 2.0f, h6 = 0.01f / 6.0f;
    float x = x0[3*b + 0], y = x0[3*b + 1], z = x0[3*b + 2];

#pragma unroll 8
    for (int t = 0; t < HALF; ++t) STEP();

    ckpt[3*b + 0] = x; ckpt[3*b + 1] = y; ckpt[3*b + 2] = z;
}

__global__ __launch_bounds__(192) void lorenz_fine(
    const float* __restrict__ x0,
    const float* __restrict__ p,
    const float* __restrict__ ckpt,
    float* __restrict__ out)
{
#pragma clang fp contract(off)
    __shared__ float buf[2][3][TT][LROWS];   // 49.9 KB -> 2 blocks/CU

    const int tid  = threadIdx.x;
    const int lane = tid & 63;
    const int half = blockIdx.x >> 8;             // 0: t 1..1000, 1: t 1001..2000
    const int b0   = (blockIdx.x & 255) * ROWS;
    const size_t obase = (size_t)half * HALF;     // time offset within row

    if (tid < 64) {
        // ================= compute wave =================
        const float p0 = p[0], p1 = p[1], p2n = -p[2];
        const float h1 = 0.01f, h2 = 0.01f / 2.0f, h6 = 0.01f / 6.0f;
        const int b = b0 + lane;
        const float* src = half ? ckpt : x0;
        float x = src[3*b + 0], y = src[3*b + 1], z = src[3*b + 2];

        if (!half) {   // t = 0 column
            size_t g = (size_t)b * (3 * TROWS);
            out[g] = x; out[g + TROWS] = y; out[g + 2*TROWS] = z;
        }

        for (int k = 0; k < NFULL; ++k) {
            float* bb = &buf[k & 1][0][0][0];
#pragma unroll 8
            for (int tl = 0; tl < TT; ++tl) {
                STEP();
                bb[              tl*LROWS + lane] = x;
                bb[  TT*LROWS  + tl*LROWS + lane] = y;
                bb[2*TT*LROWS  + tl*LROWS + lane] = z;
            }
            __syncthreads();                  // tile k ready
        }
#pragma unroll
        for (int tl = 0; tl < TAIL; ++tl) {   // tail -> buf 1 (31 is odd)
            STEP();
            buf[1][0][tl][lane] = x;
            buf[1][1][tl][lane] = y;
            buf[1][2][tl][lane] = z;
        }
        __syncthreads();                      // tail ready
    } else {
        // ================= writer waves =================
        const int w     = (tid >> 6) - 1;     // 0 or 1
        const int rbase = w * 32;             // rows [rbase, rbase+32)
        const int tloc  = lane & 31;
        const int rofs  = lane >> 5;          // 0 or 1

        for (int k = 0; k < NFULL; ++k) {
            __syncthreads();                  // wait: tile k ready
            const float* bb = &buf[k & 1][0][0][0];
            int r = rbase + rofs;
            size_t g = (size_t)(b0 + r) * (3 * TROWS) + obase + 1 + (size_t)k * TT + tloc;
#pragma unroll 4
            for (int i = 0; i < 16; ++i) {    // 2 rows per instruction
                out[g]             = bb[              tloc*LROWS + r];
                out[g +     TROWS] = bb[  TT*LROWS  + tloc*LROWS + r];
                out[g + 2 * TROWS] = bb[2*TT*LROWS  + tloc*LROWS + r];
                r += 2;
                g += (size_t)2 * (3 * TROWS);
            }
        }
        __syncthreads();                      // wait: tail ready
        {
            const float* bb = &buf[1][0][0][0];
            const int tt = lane & 7;          // 8 t-values
            int r = rbase + (lane >> 3);      // 8 rows per instruction
            size_t g = (size_t)(b0 + r) * (3 * TROWS) + obase + 1 + (size_t)NFULL * TT + tt;
#pragma unroll
            for (int i = 0; i < 4; ++i) {
                out[g]             = bb[              tt*LROWS + r];
                out[g +     TROWS] = bb[  TT*LROWS  + tt*LROWS + r];
                out[g + 2 * TROWS] = bb[2*TT*LROWS  + tt*LROWS + r];
                r += 8;
                g += (size_t)8 * (3 * TROWS);
            }
        }
    }
}

extern "C" void kernel_launch(void* const* d_in, const int* in_sizes, int n_in,
                              void* d_out, int out_size, void* d_ws, size_t ws_size,
                              hipStream_t stream)
{
    const float* x0  = (const float*)d_in[0];
    const float* p   = (const float*)d_in[1];
    float*       out = (float*)d_out;
    float*       ckpt = (float*)d_ws;     // 16384*3 floats = 192 KB

    const int B = in_sizes[0] / 3;        // 16384
    const int nb = B / ROWS;              // 256

    lorenz_coarse<<<nb,     64, 0, stream>>>(x0, p, ckpt);
    lorenz_fine  <<<2 * nb, 192, 0, stream>>>(x0, p, ckpt, out);
}

// Round 11
// 185.149 us; speedup vs baseline: 1.4288x; 1.4288x over previous
//
#include <hip/hip_runtime.h>

// Lorenz RK4, B=16384, NT=2000, dt=0.01. out[b*6003 + d*2001 + t].
//
// Round-11: writer overhaul for DRAM page locality. Evidence (R6 split):
// compute wall ~205 cyc/step (~171us) AND write wall ~2.3 TB/s (~171us) are
// EQUAL — all single-sided changes were null. This round: longer contiguous
// runs (TT=96 -> 384B), dwordx4 nontemporal stores, LDS [p][row][t] with odd
// stride 97 (compute ds_writes stay 2-way conflict-free; writer packing
// reads are conflicted but writer has 4x slack). Math untouched: absmax
// must stay exactly 0.0078125.

#define TROWS  2001
#define ROWS   64
#define T0TILE 63          // tile 0: out idx 1..63
#define TTILE  96          // tiles 1..20: out idx 96k-32 .. 96k+63
#define NTILE  20
#define TAILN  17          // tail: out idx 1984..2000
#define LSTR   97          // odd LDS row stride (words)

typedef float f4 __attribute__((ext_vector_type(4), aligned(4)));

#define FMA(a,b,c) __builtin_fmaf((a),(b),(c))

#define STEP() do {                                                          \
        float k1x = p0 * (y - x);                                            \
        float k1y = FMA(x, p1 - z, -y);                                      \
        float k1z = FMA(p2n, z, x * y);                                      \
        float ax = FMA(h2,k1x,x), ay = FMA(h2,k1y,y), az = FMA(h2,k1z,z);    \
        float k2x = p0 * (ay - ax);                                          \
        float k2y = FMA(ax, p1 - az, -ay);                                   \
        float k2z = FMA(p2n, az, ax * ay);                                   \
        float bx = FMA(h2,k2x,x), by = FMA(h2,k2y,y), bz = FMA(h2,k2z,z);    \
        float k3x = p0 * (by - bx);                                          \
        float k3y = FMA(bx, p1 - bz, -by);                                   \
        float k3z = FMA(p2n, bz, bx * by);                                   \
        float cx = FMA(h1,k3x,x), cy = FMA(h1,k3y,y), cz = FMA(h1,k3z,z);    \
        float k4x = p0 * (cy - cx);                                          \
        float k4y = FMA(cx, p1 - cz, -cy);                                   \
        float k4z = FMA(p2n, cz, cx * cy);                                   \
        float sx = FMA(2.0f,k2x,k1x); sx = FMA(2.0f,k3x,sx); sx += k4x;      \
        float sy = FMA(2.0f,k2y,k1y); sy = FMA(2.0f,k3y,sy); sy += k4y;      \
        float sz = FMA(2.0f,k2z,k1z); sz = FMA(2.0f,k3z,sz); sz += k4z;      \
        x = FMA(h6,sx,x); y = FMA(h6,sy,y); z = FMA(h6,sz,z);                \
    } while (0)

__global__ __launch_bounds__(192) void lorenz_rk4(
    const float* __restrict__ x0,
    const float* __restrict__ p,
    float* __restrict__ out)
{
#pragma clang fp contract(off)
    // [buf][plane][row][t], stride 97: 2*3*64*97*4 = 148,992 B (1 block/CU)
    __shared__ float buf[2][3][ROWS][LSTR];

    const int tid  = threadIdx.x;
    const int lane = tid & 63;
    const int b0   = blockIdx.x * ROWS;

    if (tid < 64) {
        // ================= compute wave =================
        const float p0 = p[0], p1 = p[1], p2n = -p[2];
        const float h1 = 0.01f, h2 = 0.01f / 2.0f, h6 = 0.01f / 6.0f;
        const int b = b0 + lane;
        float x = x0[3*b + 0], y = x0[3*b + 1], z = x0[3*b + 2];

        {   // t = 0 column
            size_t g = (size_t)b * (3 * TROWS);
            out[g] = x; out[g + TROWS] = y; out[g + 2*TROWS] = z;
        }

        // compute-wave LDS write: addr word = p*(64*97) + lane*97 + t
        //  -> bank (lane + t) % 32, 2-way = free.
        // tile 0: 63 steps -> buf 0
        float* r0 = &buf[0][0][lane][0];
#pragma unroll 7
        for (int tl = 0; tl < T0TILE; ++tl) {
            STEP();
            r0[tl]                 = x;
            r0[tl +   ROWS*LSTR]   = y;
            r0[tl + 2*ROWS*LSTR]   = z;
        }
        __syncthreads();                      // tile 0 ready

        for (int k = 1; k <= NTILE; ++k) {
            float* rr = &buf[k & 1][0][lane][0];
#pragma unroll 8
            for (int tl = 0; tl < TTILE; ++tl) {
                STEP();
                rr[tl]                 = x;
                rr[tl +   ROWS*LSTR]   = y;
                rr[tl + 2*ROWS*LSTR]   = z;
            }
            __syncthreads();                  // tile k ready
        }

        // tail: 17 steps -> buf[(NTILE+1)&1] = buf[1]
        float* rt = &buf[1][0][lane][0];
#pragma unroll
        for (int tl = 0; tl < TAILN; ++tl) {
            STEP();
            rt[tl]                 = x;
            rt[tl +   ROWS*LSTR]   = y;
            rt[tl + 2*ROWS*LSTR]   = z;
        }
        __syncthreads();                      // tail ready
    } else {
        // ================= writer waves =================
        const int w     = (tid >> 6) - 1;     // 0 or 1
        const int rbase = w * 32;             // rows [rbase, rbase+32)

        // ---- tile 0: 63 values, out idx 1..63 (scalar, lane = t) ----
        __syncthreads();
        {
            const int t = lane;
            if (t < T0TILE) {
#pragma unroll 4
                for (int r = rbase; r < rbase + 32; ++r) {
                    size_t g = (size_t)(b0 + r) * (3 * TROWS) + 1 + t;
                    __builtin_nontemporal_store(buf[0][0][r][t], &out[g]);
                    __builtin_nontemporal_store(buf[0][1][r][t], &out[g + TROWS]);
                    __builtin_nontemporal_store(buf[0][2][r][t], &out[g + 2*TROWS]);
                }
            }
        }

        // ---- tiles 1..20: 96 values each, out idx 96k-32 .. 96k+63 ----
        // lanes 0..23 of each half-wave pack float4 chunks (c = 4*(lane&31)).
        for (int k = 1; k <= NTILE; ++k) {
            __syncthreads();                  // tile k ready
            const int cl  = lane & 31;
            const int rof = lane >> 5;
            if (cl < 24) {
                const int tl0 = 4 * cl;       // 0..92
                const size_t obase = (size_t)TTILE * k - 32 + tl0;
#pragma unroll 4
                for (int rp = 0; rp < 16; ++rp) {
                    const int r = rbase + 2*rp + rof;
                    const float* q = &buf[k & 1][0][r][tl0];
                    size_t g = (size_t)(b0 + r) * (3 * TROWS) + obase;
#pragma unroll
                    for (int pl = 0; pl < 3; ++pl) {
                        f4 v = { q[0], q[1], q[2], q[3] };
                        __builtin_nontemporal_store(v, (f4*)(out + g));
                        q += ROWS * LSTR;
                        g += TROWS;
                    }
                }
            }
        }

        // ---- tail: 17 values, out idx 1984..2000 (scalar, lane = t) ----
        __syncthreads();                      // tail ready
        {
            const int t = lane;
            if (t < TAILN) {
#pragma unroll 4
                for (int r = rbase; r < rbase + 32; ++r) {
                    size_t g = (size_t)(b0 + r) * (3 * TROWS) + 1984 + t;
                    __builtin_nontemporal_store(buf[1][0][r][t], &out[g]);
                    __builtin_nontemporal_store(buf[1][1][r][t], &out[g + TROWS]);
                    __builtin_nontemporal_store(buf[1][2][r][t], &out[g + 2*TROWS]);
                }
            }
        }
    }
}

extern "C" void kernel_launch(void* const* d_in, const int* in_sizes, int n_in,
                              void* d_out, int out_size, void* d_ws, size_t ws_size,
                              hipStream_t stream)
{
    const float* x0  = (const float*)d_in[0];
    const float* p   = (const float*)d_in[1];
    float*       out = (float*)d_out;

    const int B = in_sizes[0] / 3;        // 16384
    const int nblocks = B / ROWS;         // 256

    lorenz_rk4<<<nblocks, 192, 0, stream>>>(x0, p, out);
}